// Round 7
// baseline (133.341 us; speedup 1.0000x reference)
//
#include <hip/hip_runtime.h>
#include <hip/hip_bf16.h>
#include <stdint.h>
#include <math.h>

// ---------- types ----------
typedef __bf16 bf16;
typedef bf16  bf16x4  __attribute__((ext_vector_type(4)));
typedef bf16  bf16x8  __attribute__((ext_vector_type(8)));
typedef float floatx4 __attribute__((ext_vector_type(4)));

#define MFMA_16x16x32_BF16(a, b, c) \
  __builtin_amdgcn_mfma_f32_16x16x32_bf16((a), (b), (c), 0, 0, 0)

// async global->LDS, 16B per lane. LDS dest is wave-uniform base + lane*16.
__device__ __forceinline__ void load_lds16(const void* g, void* l) {
  __builtin_amdgcn_global_load_lds(
      (const __attribute__((address_space(1))) unsigned int*)g,
      (__attribute__((address_space(3))) unsigned int*)l, 16, 0, 0);
}

// ---------- constants ----------
// B=2, L=2048, D=1024, H=16, dh=64, WINDOW=256
#define LSEQ 2048
#define DMODEL 1024
#define NH 16
#define DH 64

// ============================================================
// 1) W^T pack only (hidden fp32->bf16 cast now fused into the GEMM's
//    A-staging — reg-staged, cvt at STAGE time, not fragment time,
//    avoiding round-1's failure mode). 32x32 tiles via LDS, z=q/k/v.
// ============================================================
__global__ void pack_w(const float* __restrict__ Wq, const float* __restrict__ Wk,
                       const float* __restrict__ Wv, uint16_t* __restrict__ Wt) {
  __shared__ float tile[32][33];
  const int p = blockIdx.x;             // 0..3071
  const int z = p >> 10;                // /1024
  const int rem = p & 1023;
  const int k0 = (rem >> 5) * 32, n0 = (rem & 31) * 32;
  const float* W = (z == 0) ? Wq : (z == 1) ? Wk : Wv;
  const int tx = threadIdx.x & 31, ty = threadIdx.x >> 5;  // 32x8
#pragma unroll
  for (int i = 0; i < 4; ++i)
    tile[ty + i * 8][tx] = W[(size_t)(k0 + ty + i * 8) * DMODEL + n0 + tx];
  __syncthreads();
  uint16_t* out = Wt + (size_t)z * DMODEL * DMODEL;
#pragma unroll
  for (int i = 0; i < 4; ++i)
    *(bf16*)&out[(size_t)(n0 + ty + i * 8) * DMODEL + k0 + tx] =
        (bf16)tile[tx][ty + i * 8];
}

// ============================================================
// 3) QKV GEMM — 128x192 tiles over the FUSED 4096x3072 output.
//    Grid 512 (2 blocks/CU), 256 threads = 4 waves, wave tile 64x96,
//    BK=64, dbuf LDS 80 KB. One __syncthreads per K-tile.
//    A is staged from the fp32 hidden DIRECTLY: issue-early reg loads
//    (compiler inserts the vmcnt waits), cvt fp32->bf16 once at stage
//    time (same RNE as the old pack -> bit-identical), ds_write_b128.
//    LDS stays all-bf16; fragment path unchanged. B via global_load_lds.
//    Columns span z: per 16-col group, z = gcol>>10 picks out/bias/scale.
//    z==2 groups transpose via dead staging LDS (32-key-panel perm) into
//    V^T [B,H,dh,L] with coalesced b128 stores.
// ============================================================
__global__ __launch_bounds__(256, 2) void qkv_gemm(
    const float* __restrict__ A,        // fp32 hidden [4096][1024]
    const uint16_t* __restrict__ Wt,
    const float* __restrict__ bq, const float* __restrict__ bk,
    const float* __restrict__ bv,
    uint16_t* __restrict__ outq, uint16_t* __restrict__ outk,
    uint16_t* __restrict__ outvt) {
  // buffer b at b*20480 u16: A tile [128][64] at 0, B tile [192][64] at 8192.
  __shared__ __attribute__((aligned(16))) uint16_t lds[40960];  // 80 KB

  const int xcd = blockIdx.x & 7;
  const int i = blockIdx.x >> 3;        // 0..63
  const int m0 = (xcd * 4 + (i & 3)) * 128;   // XCD owns 4 panels (L2-resident)
  const int n0 = (i >> 2) * 192;        // 0..2880 in fused 3072-col space

  const int t = threadIdx.x;
  const int lane = t & 63;
  const int w = t >> 6;                 // 0..3
  const int wm = (w >> 1) * 64;
  const int wn = (w & 1) * 96;
  const int col = lane & 15;
  const int quad = lane >> 4;

  floatx4 acc[4][6] = {};

  // B staging: 1536 16B-chunks via global_load_lds, 6/thread.
  // XOR swizzle on the GLOBAL k-chunk: slot sl of row r holds chunk sl^(r&7).
  auto stageB = [&](int kt, int bi) {
    const int k0 = kt * 64;
    uint16_t* base = &lds[bi * 20480];
#pragma unroll
    for (int c = 0; c < 6; ++c) {
      int cb = t + c * 256;             // 0..1535, rows 0..191
      int row = cb >> 3, sl = cb & 7;
      int gc = n0 + row;                // fused col 0..3071
      const uint16_t* g = Wt + ((size_t)(gc >> 10) << 20) +
                          (size_t)(gc & 1023) * DMODEL + k0 +
                          ((sl ^ (row & 7)) * 8);
      load_lds16(g, &base[8192 + cb * 8]);
    }
  };
  // A staging, phase 1: issue 8 float4 loads (4 chunks x 32B fp32) to regs.
  auto issueA = [&](int kt, float4* areg) {
    const int k0 = kt * 64;
#pragma unroll
    for (int c = 0; c < 4; ++c) {
      int chunk = t + c * 256;          // 0..1023, rows 0..127
      int row = chunk >> 3, sl = chunk & 7;
      const float* g = A + (size_t)(m0 + row) * DMODEL + k0 + ((sl ^ (row & 7)) * 8);
      areg[c * 2]     = *(const float4*)g;
      areg[c * 2 + 1] = *(const float4*)(g + 4);
    }
  };
  // A staging, phase 2: cvt to bf16 (RNE, == old pack) + ds_write_b128.
  auto writeA = [&](int bi, const float4* areg) {
    uint16_t* base = &lds[bi * 20480];
#pragma unroll
    for (int c = 0; c < 4; ++c) {
      int chunk = t + c * 256;
      bf16x8 v;
      v[0] = (bf16)areg[c * 2].x;     v[1] = (bf16)areg[c * 2].y;
      v[2] = (bf16)areg[c * 2].z;     v[3] = (bf16)areg[c * 2].w;
      v[4] = (bf16)areg[c * 2 + 1].x; v[5] = (bf16)areg[c * 2 + 1].y;
      v[6] = (bf16)areg[c * 2 + 1].z; v[7] = (bf16)areg[c * 2 + 1].w;
      *(bf16x8*)&base[chunk * 8] = v;
    }
  };

  // prologue: tile 0 fully staged (writeA stalls on its own loads, once).
  {
    float4 areg[8];
    issueA(0, areg);
    writeA(0, areg);
    stageB(0, 0);
  }

  for (int kt = 0; kt < 16; ++kt) {
    const uint16_t* buf = &lds[(kt & 1) * 20480];
    const int nbi = (kt + 1) & 1;

    // vmcnt(0)+lgkmcnt(0)+barrier: tile kt (gload_lds B + ds_write A)
    // visible to all waves; everyone done reading buf[nbi].
    __syncthreads();
    __builtin_amdgcn_sched_barrier(0);
    float4 areg[8];
    if (kt < 15) {
      issueA(kt + 1, areg);             // in flight across the body
      stageB(kt + 1, nbi);
    }
    __builtin_amdgcn_sched_barrier(0);

    // all 20 frag reads up-front; compiler's lgkmcnt pipelines MFMAs
    // under the later reads. khalf0 = k-chunks quad, khalf1 = 4+quad.
    bf16x8 a0[4], b0[6], a1[4], b1[6];
#pragma unroll
    for (int mi = 0; mi < 4; ++mi) {
      int r = wm + mi * 16 + col;
      a0[mi] = *(const bf16x8*)&buf[r * 64 + ((quad ^ (r & 7)) * 8)];
    }
#pragma unroll
    for (int nj = 0; nj < 6; ++nj) {
      int r = wn + nj * 16 + col;
      b0[nj] = *(const bf16x8*)&buf[8192 + r * 64 + ((quad ^ (r & 7)) * 8)];
    }
#pragma unroll
    for (int mi = 0; mi < 4; ++mi) {
      int r = wm + mi * 16 + col;
      a1[mi] = *(const bf16x8*)&buf[r * 64 + (((4 + quad) ^ (r & 7)) * 8)];
    }
#pragma unroll
    for (int nj = 0; nj < 6; ++nj) {
      int r = wn + nj * 16 + col;
      b1[nj] = *(const bf16x8*)&buf[8192 + r * 64 + (((4 + quad) ^ (r & 7)) * 8)];
    }

    __builtin_amdgcn_s_setprio(1);
#pragma unroll
    for (int mi = 0; mi < 4; ++mi)
#pragma unroll
      for (int nj = 0; nj < 6; ++nj)
        acc[mi][nj] = MFMA_16x16x32_BF16(a0[mi], b0[nj], acc[mi][nj]);
    __builtin_amdgcn_s_setprio(0);

    // A-loads have landed by now (~1500 cy of MFMA); cvt+write mid-body
    // keeps peak VGPR down (a0/b0 dead) and hides the LDS writes.
    if (kt < 15) writeA(nbi, areg);

    __builtin_amdgcn_s_setprio(1);
#pragma unroll
    for (int mi = 0; mi < 4; ++mi)
#pragma unroll
      for (int nj = 0; nj < 6; ++nj)
        acc[mi][nj] = MFMA_16x16x32_BF16(a1[mi], b1[nj], acc[mi][nj]);
    __builtin_amdgcn_s_setprio(0);
  }
  // drain + all waves done with staging LDS before V^T reuse.
  __syncthreads();

  // epilogue: C/D layout col=lane&15 (n), row=quad*4+reg (m); z per 16-col
  // group (1024 % 16 == 0 -> z uniform within a group).
  const int bI = m0 >> 11, l0 = m0 & 2047;   // batch, 128-aligned l base

  // ---- q/k (z<2) groups: direct scattered bf16 stores ----
#pragma unroll
  for (int nj = 0; nj < 6; ++nj) {
    int gc = n0 + wn + nj * 16 + col;   // fused col
    int zz = gc >> 10, rem = gc & 1023;
    if (zz != 2) {
      const float* biasp = (zz == 0) ? bq : bk;
      uint16_t* outp = (zz == 0) ? outq : outk;
      const float scale = (zz == 0) ? 0.125f : 1.0f;  // fold 1/sqrt(dh) into q
      float bb = biasp[rem];
      int h = rem >> 6, d = rem & 63;
#pragma unroll
      for (int mi = 0; mi < 4; ++mi) {
#pragma unroll
        for (int r = 0; r < 4; ++r) {
          int l = l0 + wm + mi * 16 + quad * 4 + r;
          *(bf16*)&outp[(((size_t)bI * NH + h) * LSEQ + l) * DH + d] =
              (bf16)((acc[mi][nj][r] + bb) * scale);
        }
      }
    }
  }

  // ---- v (z==2) groups: transpose via LDS (stride 136) with the
  //      32-key-panel permutation baked in, then coalesced b128 stores.
  const int c2 = 2048 - n0;             // local col where z==2 starts
  if (c2 < 192) {
    const int lo2 = c2 < 0 ? 0 : c2;
    __syncthreads();                    // staging buffers fully dead
#pragma unroll
    for (int nj = 0; nj < 6; ++nj) {
      int nloc = wn + nj * 16 + col;
      int gc = n0 + nloc;
      if (gc >= 2048) {
        float bb = bv[gc - 2048];
#pragma unroll
        for (int mi = 0; mi < 4; ++mi) {
          int mb = wm + mi * 16 + quad * 4;    // local l, 0..124 (mult of 4)
          int pp = (mb & ~31) | (((mb >> 2) & 3) << 3) | (((mb >> 4) & 1) << 2);
#pragma unroll
          for (int r = 0; r < 4; ++r)
            *(bf16*)&lds[nloc * 136 + pp + r] = (bf16)(acc[mi][nj][r] + bb);
        }
      }
    }
    __syncthreads();
    // cooperative stores: cols lo2..191, 16 chunks of 8 l-values each.
    const int cnt = (192 - lo2) * 16;   // 1024 or 3072 (block-uniform)
    for (int idx = t; idx < cnt; idx += 256) {
      int nloc = lo2 + (idx >> 4), ch = idx & 15;
      int rem = n0 + nloc - 2048;
      int h = rem >> 6, d = rem & 63;
      uint16_t* dst =
          &outvt[(((size_t)bI * NH + h) * DH + d) * LSEQ + l0 + ch * 8];
      *(bf16x8*)dst = *(const bf16x8*)&lds[nloc * 136 + ch * 8];
    }
  }
}

// ============================================================
// 4) windowed attention, block-cooperative LDS staging, 64-KEY CHUNKS.
//    K tile 64x64, V^T tile 64d x 64keys (two permuted 32-key panels),
//    both double-buffered (32 KB LDS, 4 blocks/CU). setprio around MFMA
//    clusters (T5 — independent blocks at different phases).
// ============================================================
__global__ __launch_bounds__(256, 4) void attn(
    const uint16_t* __restrict__ Q, const uint16_t* __restrict__ K,
    const uint16_t* __restrict__ Vt, float* __restrict__ out) {
  __shared__ __attribute__((aligned(16))) uint16_t kbuf[2][4096];  // 64 keys x 64 d
  __shared__ __attribute__((aligned(16))) uint16_t vbuf[2][4096];  // 64 d x 64 keys

  const int t = threadIdx.x;
  const int lane = t & 63;
  const int w = t >> 6;
  const int xcd = blockIdx.x & 7;
  const int slot = blockIdx.x >> 3;          // 0..127
  const int bh = xcd * 4 + (slot >> 5);      // 4 heads per XCD
  const int q0 = (slot & 31) * 64;           // block's query base
  const int q0w = q0 + w * 16;               // this wave's 16 queries
  const int b = bh >> 4, h = bh & 15;
  const uint16_t* Qp = Q + (size_t)bh * LSEQ * DH;
  const uint16_t* Kp = K + (size_t)bh * LSEQ * DH;
  const uint16_t* Vp = Vt + (size_t)bh * DH * LSEQ;
  const int col = lane & 15, quad = lane >> 4;

  bf16x8 qf0 = *(const bf16x8*)&Qp[(size_t)(q0w + col) * DH + quad * 8];
  bf16x8 qf1 = *(const bf16x8*)&Qp[(size_t)(q0w + col) * DH + 32 + quad * 8];

  bf16x8 ones;
#pragma unroll
  for (int u = 0; u < 8; ++u) ones[u] = (bf16)1.0f;

  // chunk c covers keys [q0-256+64c, +64); skip fully-negative chunks.
  const int c_start = (q0 < 256) ? ((256 - q0) >> 6) : 0;

  floatx4 o[4] = {};                    // O^T: d=nj*16+quad*4+r, q=col
  floatx4 lac = {0.f, 0.f, 0.f, 0.f};   // row sums (all regs equal l[q=col])

  auto stage = [&](int c, int bi) {
    const int kc = q0 - 256 + 64 * c;   // >= 0 by construction
    int ci = w * 64 + lane;
    {
      int row = ci >> 3, s = ci & 7;    // rows 0..31
      const uint16_t* g = Kp + (size_t)(kc + row) * DH + ((s ^ (row & 7)) * 8);
      load_lds16(g, &kbuf[bi][w * 512]);
      int row2 = row + 32;              // rows 32..63
      const uint16_t* g2 = Kp + (size_t)(kc + row2) * DH + ((s ^ (row2 & 7)) * 8);
      load_lds16(g2, &kbuf[bi][2048 + w * 512]);
    }
    {
      int d = ci >> 3, s = ci & 7;      // d 0..31
      const uint16_t* g = Vp + (size_t)d * LSEQ + kc + ((s ^ (d & 7)) * 8);
      load_lds16(g, &vbuf[bi][w * 512]);
      int d2 = d + 32;                  // d 32..63
      const uint16_t* g2 = Vp + (size_t)d2 * LSEQ + kc + ((s ^ (d2 & 7)) * 8);
      load_lds16(g2, &vbuf[bi][2048 + w * 512]);
    }
  };

  stage(c_start, c_start & 1);

  for (int c = c_start; c <= 4; ++c) {
    __syncthreads();                    // drains vmcnt: buf[c&1] ready
    if (c < 4) stage(c + 1, (c + 1) & 1);

    const int kc = q0 - 256 + 64 * c;
    const int hi = q0w + 15, lo = q0w - 255;
    if (kc <= hi && kc + 64 > lo) {     // chunk intersects this wave's window
      const uint16_t* kb_ = kbuf[c & 1];
      const uint16_t* vb_ = vbuf[c & 1];

      // S^T = K . Q^T : A = K rows (m=key), B = Q (n=query); 4 key-subtiles
      floatx4 sT[4] = {{0,0,0,0},{0,0,0,0},{0,0,0,0},{0,0,0,0}};
      __builtin_amdgcn_s_setprio(1);
#pragma unroll
      for (int sub = 0; sub < 4; ++sub) {
        int r_ = sub * 16 + col;        // key row in 64-row tile
        bf16x8 ka  = *(const bf16x8*)&kb_[r_ * 64 + ((quad ^ (r_ & 7)) * 8)];
        bf16x8 kb2 = *(const bf16x8*)&kb_[r_ * 64 + (((4 + quad) ^ (r_ & 7)) * 8)];
        sT[sub] = MFMA_16x16x32_BF16(ka, qf0, sT[sub]);
        sT[sub] = MFMA_16x16x32_BF16(kb2, qf1, sT[sub]);
      }
      __builtin_amdgcn_s_setprio(0);

      // per-query band mask + exp; pack two P^T B-frags (one per 32-key panel)
      // panel-local mapping: key(quad,j) = (j>>2)*16 + quad*4 + (j&3).
      const bool needm = (kc < q0w - 240) | (kc + 63 > q0w);
      const int q = q0w + col;
      bf16x8 pb[2];
#pragma unroll
      for (int sel = 0; sel < 2; ++sel) {
#pragma unroll
        for (int sp = 0; sp < 2; ++sp) {
#pragma unroll
          for (int r = 0; r < 4; ++r) {
            float v = sT[sel * 2 + sp][r];
            if (needm) {
              int key = kc + sel * 32 + sp * 16 + quad * 4 + r;
              v = ((key <= q) & (key > q - 256)) ? v : -INFINITY;  // exp(-inf)=0
            }
            pb[sel][sp * 4 + r] = (bf16)__expf(v);
          }
        }
      }

      // O^T += V^T . P^T — one b128 A-frag per (nj, panel)
      __builtin_amdgcn_s_setprio(1);
#pragma unroll
      for (int nj = 0; nj < 4; ++nj) {
        int d = nj * 16 + col;
        bf16x8 va0 = *(const bf16x8*)&vb_[d * 64 + ((quad ^ (d & 7)) * 8)];
        bf16x8 va1 = *(const bf16x8*)&vb_[d * 64 + (((4 + quad) ^ (d & 7)) * 8)];
        o[nj] = MFMA_16x16x32_BF16(va0, pb[0], o[nj]);
        o[nj] = MFMA_16x16x32_BF16(va1, pb[1], o[nj]);
      }
      lac = MFMA_16x16x32_BF16(ones, pb[0], lac);
      lac = MFMA_16x16x32_BF16(ones, pb[1], lac);
      __builtin_amdgcn_s_setprio(0);
    }
  }

  float rinv = 1.0f / lac[0];           // all lac regs equal l[q=col]
#pragma unroll
  for (int nj = 0; nj < 4; ++nj) {
    float4 v4;
    v4.x = o[nj][0] * rinv; v4.y = o[nj][1] * rinv;
    v4.z = o[nj][2] * rinv; v4.w = o[nj][3] * rinv;
    *(float4*)&out[((size_t)b * LSEQ + q0w + col) * DMODEL + h * DH + nj * 16 + quad * 4] = v4;
  }
}

// ============================================================
// launch
// ============================================================
extern "C" void kernel_launch(void* const* d_in, const int* in_sizes, int n_in,
                              void* d_out, int out_size, void* d_ws, size_t ws_size,
                              hipStream_t stream) {
  const float* hidden = (const float*)d_in[0];
  const float* Wq = (const float*)d_in[1];
  const float* bq = (const float*)d_in[2];
  const float* Wk = (const float*)d_in[3];
  const float* bk = (const float*)d_in[4];
  const float* Wv = (const float*)d_in[5];
  const float* bv = (const float*)d_in[6];
  float* out = (float*)d_out;

  // workspace layout (bytes): needs 30 MB
  char* ws = (char*)d_ws;
  uint16_t* Wt  = (uint16_t*)(ws);                       // 6 MB  bf16 W^T x3
  uint16_t* qb  = (uint16_t*)(ws + ((size_t)6  << 20));  // 8 MB  q*0.125 [B,H,L,dh]
  uint16_t* kb  = (uint16_t*)(ws + ((size_t)14 << 20));  // 8 MB  k [B,H,L,dh]
  uint16_t* vtb = (uint16_t*)(ws + ((size_t)22 << 20));  // 8 MB  v^T perm [B,H,dh,L]

  pack_w<<<3072, 256, 0, stream>>>(Wq, Wk, Wv, Wt);
  qkv_gemm<<<512, 256, 0, stream>>>(hidden, Wt, bq, bk, bv, qb, kb, vtb);
  attn<<<1024, 256, 0, stream>>>(qb, kb, vtb, out);
}

// Round 8
// 126.999 us; speedup vs baseline: 1.0499x; 1.0499x over previous
//
#include <hip/hip_runtime.h>
#include <hip/hip_bf16.h>
#include <stdint.h>
#include <math.h>

// ---------- types ----------
typedef __bf16 bf16;
typedef bf16  bf16x4  __attribute__((ext_vector_type(4)));
typedef bf16  bf16x8  __attribute__((ext_vector_type(8)));
typedef float floatx4 __attribute__((ext_vector_type(4)));

#define MFMA_16x16x32_BF16(a, b, c) \
  __builtin_amdgcn_mfma_f32_16x16x32_bf16((a), (b), (c), 0, 0, 0)

// async global->LDS, 16B per lane. LDS dest is wave-uniform base + lane*16.
__device__ __forceinline__ void load_lds16(const void* g, void* l) {
  __builtin_amdgcn_global_load_lds(
      (const __attribute__((address_space(1))) unsigned int*)g,
      (__attribute__((address_space(3))) unsigned int*)l, 16, 0, 0);
}

// ---------- constants ----------
// B=2, L=2048, D=1024, H=16, dh=64, WINDOW=256
#define LSEQ 2048
#define DMODEL 1024
#define NH 16
#define DH 64

// ============================================================
// 1) merged pack: blocks 0..4095 -> hidden fp32->bf16;
//    blocks 4096..7167 -> W^T bf16 transpose (32x32 tiles, z=q/k/v).
//    The 8 MB bf16 A-copy is the price of the clean global_load_lds
//    A-path in the GEMM — fp32-A fusion refuted twice (R1: LDS-bytes
//    amplification; R7: register-pressure schedule collapse).
// ============================================================
__global__ void pack_all(const float4* __restrict__ x, uint16_t* __restrict__ y,
                         const float* __restrict__ Wq, const float* __restrict__ Wk,
                         const float* __restrict__ Wv, uint16_t* __restrict__ Wt) {
  const int bi = blockIdx.x;
  if (bi < 4096) {
    int i = bi * 256 + threadIdx.x;
    float4 f = x[i];
    bf16x4 v;
    v[0] = (bf16)f.x; v[1] = (bf16)f.y; v[2] = (bf16)f.z; v[3] = (bf16)f.w;
    *(bf16x4*)&y[(size_t)i * 4] = v;
    return;
  }
  __shared__ float tile[32][33];
  const int p = bi - 4096;              // 0..3071
  const int z = p >> 10;                // /1024
  const int rem = p & 1023;
  const int k0 = (rem >> 5) * 32, n0 = (rem & 31) * 32;
  const float* W = (z == 0) ? Wq : (z == 1) ? Wk : Wv;
  const int tx = threadIdx.x & 31, ty = threadIdx.x >> 5;  // 32x8
#pragma unroll
  for (int i = 0; i < 4; ++i)
    tile[ty + i * 8][tx] = W[(size_t)(k0 + ty + i * 8) * DMODEL + n0 + tx];
  __syncthreads();
  uint16_t* out = Wt + (size_t)z * DMODEL * DMODEL;
#pragma unroll
  for (int i = 0; i < 4; ++i)
    *(bf16*)&out[(size_t)(n0 + ty + i * 8) * DMODEL + k0 + tx] =
        (bf16)tile[tx][ty + i * 8];
}

// ============================================================
// 3) QKV GEMM — 128x192 tiles over the FUSED 4096x3072 output.
//    Grid 512 (all 256 CUs, 2 blocks/CU), 256 threads = 4 waves,
//    wave tile 64x96 (acc[4][6]), BK=64, dbuf LDS = 80 KB (2/CU exact).
//    All 20 frag ds_reads issue up-front (fits 256-reg cap at 2 w/SIMD)
//    -> compiler's fine lgkmcnt pipelines reads under MFMAs; two
//    independent blocks/CU desync read-bursts vs MFMA-bursts.
//    One barrier + vmcnt(0) per K-tile (loads issued one body earlier).
//    Columns span z: per 16-col group, z = gcol>>10 picks out/bias/scale.
//    V is written PLAIN [B,H,L,dh] (transpose in vtrans).
// ============================================================
__global__ __launch_bounds__(256, 2) void qkv_gemm(
    const uint16_t* __restrict__ A, const uint16_t* __restrict__ Wt,
    const float* __restrict__ bq, const float* __restrict__ bk,
    const float* __restrict__ bv,
    uint16_t* __restrict__ outq, uint16_t* __restrict__ outk,
    uint16_t* __restrict__ outv) {
  // buffer b at b*20480 u16: A tile [128][64] at 0, B tile [192][64] at 8192.
  __shared__ __attribute__((aligned(16))) uint16_t lds[40960];  // 80 KB

  const int xcd = blockIdx.x & 7;
  const int i = blockIdx.x >> 3;        // 0..63
  const int m0 = (xcd * 4 + (i & 3)) * 128;   // XCD owns 4 panels (1MB A in L2)
  const int n0 = (i >> 2) * 192;        // 0..2880 in fused 3072-col space

  const int t = threadIdx.x;
  const int lane = t & 63;
  const int w = t >> 6;                 // 0..3
  const int wm = (w >> 1) * 64;
  const int wn = (w & 1) * 96;
  const int col = lane & 15;
  const int quad = lane >> 4;

  floatx4 acc[4][6] = {};

  // stage K-tile kt into buffer bi: A 1024 + B 1536 16B-chunks, 10/thread.
  // LDS dest linear; XOR swizzle on the GLOBAL k-chunk (involution):
  // slot sl of row r holds k-chunk sl^(r&7).
  auto stage = [&](int kt, int bi) {
    const int k0 = kt * 64;
    uint16_t* base = &lds[bi * 20480];
#pragma unroll
    for (int c = 0; c < 10; ++c) {
      int chunk = t + c * 256;          // 0..2559
      if (chunk < 1024) {               // A rows 0..127
        int row = chunk >> 3, sl = chunk & 7;
        const uint16_t* g =
            A + (size_t)(m0 + row) * DMODEL + k0 + ((sl ^ (row & 7)) * 8);
        load_lds16(g, &base[chunk * 8]);
      } else {                          // B rows 0..191 (z-split per row)
        int cb = chunk - 1024;
        int row = cb >> 3, sl = cb & 7;
        int gc = n0 + row;              // fused col 0..3071
        const uint16_t* g = Wt + ((size_t)(gc >> 10) << 20) +
                            (size_t)(gc & 1023) * DMODEL + k0 +
                            ((sl ^ (row & 7)) * 8);
        load_lds16(g, &base[8192 + cb * 8]);
      }
    }
  };

  stage(0, 0);
  for (int kt = 0; kt < 16; ++kt) {
    const uint16_t* buf = &lds[(kt & 1) * 20480];

    // tile kt's 10 loads done (issued one full body ago -> wait ~free).
    asm volatile("s_waitcnt vmcnt(0)" ::: "memory");
    __builtin_amdgcn_s_barrier();       // kt visible; buf[nbi] free
    __builtin_amdgcn_sched_barrier(0);
    if (kt < 15) stage(kt + 1, (kt + 1) & 1);
    __builtin_amdgcn_sched_barrier(0);

    // all 20 frag reads up-front; compiler's lgkmcnt pipelines MFMAs under
    // the later reads. khalf0 = k-chunks quad, khalf1 = 4+quad.
    bf16x8 a0[4], b0[6], a1[4], b1[6];
#pragma unroll
    for (int mi = 0; mi < 4; ++mi) {
      int r = wm + mi * 16 + col;
      a0[mi] = *(const bf16x8*)&buf[r * 64 + ((quad ^ (r & 7)) * 8)];
    }
#pragma unroll
    for (int nj = 0; nj < 6; ++nj) {
      int r = wn + nj * 16 + col;
      b0[nj] = *(const bf16x8*)&buf[8192 + r * 64 + ((quad ^ (r & 7)) * 8)];
    }
#pragma unroll
    for (int mi = 0; mi < 4; ++mi) {
      int r = wm + mi * 16 + col;
      a1[mi] = *(const bf16x8*)&buf[r * 64 + (((4 + quad) ^ (r & 7)) * 8)];
    }
#pragma unroll
    for (int nj = 0; nj < 6; ++nj) {
      int r = wn + nj * 16 + col;
      b1[nj] = *(const bf16x8*)&buf[8192 + r * 64 + (((4 + quad) ^ (r & 7)) * 8)];
    }

    __builtin_amdgcn_s_setprio(1);
#pragma unroll
    for (int mi = 0; mi < 4; ++mi)
#pragma unroll
      for (int nj = 0; nj < 6; ++nj)
        acc[mi][nj] = MFMA_16x16x32_BF16(a0[mi], b0[nj], acc[mi][nj]);
    __builtin_amdgcn_s_setprio(0);
    __builtin_amdgcn_s_setprio(1);
#pragma unroll
    for (int mi = 0; mi < 4; ++mi)
#pragma unroll
      for (int nj = 0; nj < 6; ++nj)
        acc[mi][nj] = MFMA_16x16x32_BF16(a1[mi], b1[nj], acc[mi][nj]);
    __builtin_amdgcn_s_setprio(0);
  }

  // epilogue: C/D layout col=lane&15 (n), row=quad*4+reg (m); z per 16-col
  // group (1024 % 16 == 0 -> uniform within group).
#pragma unroll
  for (int nj = 0; nj < 6; ++nj) {
    int gc = n0 + wn + nj * 16 + col;   // fused col
    int zz = gc >> 10, rem = gc & 1023;
    const float* biasp = (zz == 0) ? bq : (zz == 1) ? bk : bv;
    uint16_t* outp = (zz == 0) ? outq : (zz == 1) ? outk : outv;
    const float scale = (zz == 0) ? 0.125f : 1.0f;
    float bb = biasp[rem];
    int h = rem >> 6, d = rem & 63;
#pragma unroll
    for (int mi = 0; mi < 4; ++mi) {
#pragma unroll
      for (int r = 0; r < 4; ++r) {
        int gm = m0 + wm + mi * 16 + quad * 4 + r;
        int b = gm >> 11, l = gm & 2047;
        *(bf16*)&outp[(((size_t)b * NH + h) * LSEQ + l) * DH + d] =
            (bf16)((acc[mi][nj][r] + bb) * scale);
      }
    }
  }
}

// ============================================================
// 3b) V transpose: [B,H,L,dh] -> [B,H,dh,L] with the 32-key-panel
//     permutation attn expects: within each aligned 32-key panel,
//     key kk stored at (kk&~31)|((kk>>2)&3)<<3|((kk>>4)&1)<<2|(kk&3).
//     64x64 tiles through LDS, coalesced b128 both sides. ~16 MB total.
// ============================================================
__global__ __launch_bounds__(256) void vtrans(const uint16_t* __restrict__ V,
                                              uint16_t* __restrict__ Vt) {
  __shared__ uint16_t tl[64 * 68];      // row d, stride 68 (pad 4)
  const int t = threadIdx.x;
  const int bh = blockIdx.x >> 5;       // 0..31
  const int l0 = (blockIdx.x & 31) * 64;
  const uint16_t* src = V + ((size_t)bh * LSEQ + l0) * DH;

  const int l = t >> 2, dc = (t & 3) * 16;   // 16 d-values per thread
  bf16x8 v0 = *(const bf16x8*)&src[(size_t)l * DH + dc];
  bf16x8 v1 = *(const bf16x8*)&src[(size_t)l * DH + dc + 8];
  const int pp = (l & 32) | (((l >> 2) & 3) << 3) | (((l >> 4) & 1) << 2) | (l & 3);
#pragma unroll
  for (int j = 0; j < 8; ++j) {
    tl[(dc + j) * 68 + pp]     = ((const uint16_t*)&v0)[j];
    tl[(dc + 8 + j) * 68 + pp] = ((const uint16_t*)&v1)[j];
  }
  __syncthreads();
  const int d = t >> 2, lc = (t & 3) * 16;
  uint16_t* dst = Vt + ((size_t)bh * DH + d) * LSEQ + l0 + lc;
  *(bf16x8*)&dst[0] = *(const bf16x8*)&tl[d * 68 + lc];
  *(bf16x8*)&dst[8] = *(const bf16x8*)&tl[d * 68 + lc + 8];
}

// ============================================================
// 4) windowed attention, block-cooperative LDS staging, 64-KEY CHUNKS.
//    K tile 64x64, V^T tile 64d x 64keys (two permuted 32-key panels),
//    both double-buffered (32 KB LDS, 4 blocks/CU). setprio around MFMA
//    clusters (T5 — independent blocks at different phases).
// ============================================================
__global__ __launch_bounds__(256, 4) void attn(
    const uint16_t* __restrict__ Q, const uint16_t* __restrict__ K,
    const uint16_t* __restrict__ Vt, float* __restrict__ out) {
  __shared__ __attribute__((aligned(16))) uint16_t kbuf[2][4096];  // 64 keys x 64 d
  __shared__ __attribute__((aligned(16))) uint16_t vbuf[2][4096];  // 64 d x 64 keys

  const int t = threadIdx.x;
  const int lane = t & 63;
  const int w = t >> 6;
  const int xcd = blockIdx.x & 7;
  const int slot = blockIdx.x >> 3;          // 0..127
  const int bh = xcd * 4 + (slot >> 5);      // 4 heads per XCD
  const int q0 = (slot & 31) * 64;           // block's query base
  const int q0w = q0 + w * 16;               // this wave's 16 queries
  const int b = bh >> 4, h = bh & 15;
  const uint16_t* Qp = Q + (size_t)bh * LSEQ * DH;
  const uint16_t* Kp = K + (size_t)bh * LSEQ * DH;
  const uint16_t* Vp = Vt + (size_t)bh * DH * LSEQ;
  const int col = lane & 15, quad = lane >> 4;

  bf16x8 qf0 = *(const bf16x8*)&Qp[(size_t)(q0w + col) * DH + quad * 8];
  bf16x8 qf1 = *(const bf16x8*)&Qp[(size_t)(q0w + col) * DH + 32 + quad * 8];

  bf16x8 ones;
#pragma unroll
  for (int u = 0; u < 8; ++u) ones[u] = (bf16)1.0f;

  // chunk c covers keys [q0-256+64c, +64); skip fully-negative chunks.
  const int c_start = (q0 < 256) ? ((256 - q0) >> 6) : 0;

  floatx4 o[4] = {};                    // O^T: d=nj*16+quad*4+r, q=col
  floatx4 lac = {0.f, 0.f, 0.f, 0.f};   // row sums (all regs equal l[q=col])

  auto stage = [&](int c, int bi) {
    const int kc = q0 - 256 + 64 * c;   // >= 0 by construction
    int ci = w * 64 + lane;
    {
      int row = ci >> 3, s = ci & 7;    // rows 0..31
      const uint16_t* g = Kp + (size_t)(kc + row) * DH + ((s ^ (row & 7)) * 8);
      load_lds16(g, &kbuf[bi][w * 512]);
      int row2 = row + 32;              // rows 32..63
      const uint16_t* g2 = Kp + (size_t)(kc + row2) * DH + ((s ^ (row2 & 7)) * 8);
      load_lds16(g2, &kbuf[bi][2048 + w * 512]);
    }
    {
      int d = ci >> 3, s = ci & 7;      // d 0..31
      const uint16_t* g = Vp + (size_t)d * LSEQ + kc + ((s ^ (d & 7)) * 8);
      load_lds16(g, &vbuf[bi][w * 512]);
      int d2 = d + 32;                  // d 32..63
      const uint16_t* g2 = Vp + (size_t)d2 * LSEQ + kc + ((s ^ (d2 & 7)) * 8);
      load_lds16(g2, &vbuf[bi][2048 + w * 512]);
    }
  };

  stage(c_start, c_start & 1);

  for (int c = c_start; c <= 4; ++c) {
    __syncthreads();                    // drains vmcnt: buf[c&1] ready
    if (c < 4) stage(c + 1, (c + 1) & 1);

    const int kc = q0 - 256 + 64 * c;
    const int hi = q0w + 15, lo = q0w - 255;
    if (kc <= hi && kc + 64 > lo) {     // chunk intersects this wave's window
      const uint16_t* kb_ = kbuf[c & 1];
      const uint16_t* vb_ = vbuf[c & 1];

      // S^T = K . Q^T : A = K rows (m=key), B = Q (n=query); 4 key-subtiles
      floatx4 sT[4] = {{0,0,0,0},{0,0,0,0},{0,0,0,0},{0,0,0,0}};
      __builtin_amdgcn_s_setprio(1);
#pragma unroll
      for (int sub = 0; sub < 4; ++sub) {
        int r_ = sub * 16 + col;        // key row in 64-row tile
        bf16x8 ka  = *(const bf16x8*)&kb_[r_ * 64 + ((quad ^ (r_ & 7)) * 8)];
        bf16x8 kb2 = *(const bf16x8*)&kb_[r_ * 64 + (((4 + quad) ^ (r_ & 7)) * 8)];
        sT[sub] = MFMA_16x16x32_BF16(ka, qf0, sT[sub]);
        sT[sub] = MFMA_16x16x32_BF16(kb2, qf1, sT[sub]);
      }
      __builtin_amdgcn_s_setprio(0);

      // per-query band mask + exp; pack two P^T B-frags (one per 32-key panel)
      // panel-local mapping: key(quad,j) = (j>>2)*16 + quad*4 + (j&3).
      const bool needm = (kc < q0w - 240) | (kc + 63 > q0w);
      const int q = q0w + col;
      bf16x8 pb[2];
#pragma unroll
      for (int sel = 0; sel < 2; ++sel) {
#pragma unroll
        for (int sp = 0; sp < 2; ++sp) {
#pragma unroll
          for (int r = 0; r < 4; ++r) {
            float v = sT[sel * 2 + sp][r];
            if (needm) {
              int key = kc + sel * 32 + sp * 16 + quad * 4 + r;
              v = ((key <= q) & (key > q - 256)) ? v : -INFINITY;  // exp(-inf)=0
            }
            pb[sel][sp * 4 + r] = (bf16)__expf(v);
          }
        }
      }

      // O^T += V^T . P^T — one b128 A-frag per (nj, panel)
      __builtin_amdgcn_s_setprio(1);
#pragma unroll
      for (int nj = 0; nj < 4; ++nj) {
        int d = nj * 16 + col;
        bf16x8 va0 = *(const bf16x8*)&vb_[d * 64 + ((quad ^ (d & 7)) * 8)];
        bf16x8 va1 = *(const bf16x8*)&vb_[d * 64 + (((4 + quad) ^ (d & 7)) * 8)];
        o[nj] = MFMA_16x16x32_BF16(va0, pb[0], o[nj]);
        o[nj] = MFMA_16x16x32_BF16(va1, pb[1], o[nj]);
      }
      lac = MFMA_16x16x32_BF16(ones, pb[0], lac);
      lac = MFMA_16x16x32_BF16(ones, pb[1], lac);
      __builtin_amdgcn_s_setprio(0);
    }
  }

  float rinv = 1.0f / lac[0];           // all lac regs equal l[q=col]
#pragma unroll
  for (int nj = 0; nj < 4; ++nj) {
    float4 v4;
    v4.x = o[nj][0] * rinv; v4.y = o[nj][1] * rinv;
    v4.z = o[nj][2] * rinv; v4.w = o[nj][3] * rinv;
    *(float4*)&out[((size_t)b * LSEQ + q0w + col) * DMODEL + h * DH + nj * 16 + quad * 4] = v4;
  }
}

// ============================================================
// launch
// ============================================================
extern "C" void kernel_launch(void* const* d_in, const int* in_sizes, int n_in,
                              void* d_out, int out_size, void* d_ws, size_t ws_size,
                              hipStream_t stream) {
  const float* hidden = (const float*)d_in[0];
  const float* Wq = (const float*)d_in[1];
  const float* bq = (const float*)d_in[2];
  const float* Wk = (const float*)d_in[3];
  const float* bk = (const float*)d_in[4];
  const float* Wv = (const float*)d_in[5];
  const float* bv = (const float*)d_in[6];
  float* out = (float*)d_out;

  // workspace layout (bytes): needs 46 MB
  char* ws = (char*)d_ws;
  uint16_t* hb  = (uint16_t*)(ws);                       // 8 MB  bf16 hidden
  uint16_t* Wt  = (uint16_t*)(ws + ((size_t)8  << 20));  // 6 MB  bf16 W^T x3
  uint16_t* qb  = (uint16_t*)(ws + ((size_t)14 << 20));  // 8 MB  q*0.125 [B,H,L,dh]
  uint16_t* kb  = (uint16_t*)(ws + ((size_t)22 << 20));  // 8 MB  k [B,H,L,dh]
  uint16_t* vb  = (uint16_t*)(ws + ((size_t)30 << 20));  // 8 MB  v [B,H,L,dh]
  uint16_t* vtb = (uint16_t*)(ws + ((size_t)38 << 20));  // 8 MB  v^T perm [B,H,dh,L]

  pack_all<<<7168, 256, 0, stream>>>((const float4*)hidden, hb, Wq, Wk, Wv, Wt);
  qkv_gemm<<<512, 256, 0, stream>>>(hb, Wt, bq, bk, bv, qb, kb, vb);
  vtrans<<<1024, 256, 0, stream>>>(vb, vtb);
  attn<<<1024, 256, 0, stream>>>(qb, kb, vtb, out);
}